// Round 1
// baseline (238.239 us; speedup 1.0000x reference)
//
#include <hip/hip_runtime.h>

// Local windowed 2D autocorrelation.
// x: [8, 64, 128, 128] fp32; out: [8, 64, 31, 31, 8, 8] fp32.
// KH=KW=8, SH=SW=4, no input padding.
// One thread per window: holds the 8x8 window in registers, computes all 64
// centered-offset autocorrelation values with fully unrolled static loops.

#define NH 31
#define NW 31
#define NBC (8 * 64)
#define NWIN (NBC * NH * NW)   // 492032

__global__ __launch_bounds__(256) void lacorr2d_kernel(
    const float* __restrict__ x, float* __restrict__ out) {
  int t = blockIdx.x * 256 + threadIdx.x;
  if (t >= NWIN) return;

  int w  = t % NW;
  int hw = t / NW;
  int h  = hw % NH;
  int bc = hw / NH;

  const float* src = x + (size_t)bc * (128 * 128) + (size_t)(h * 4) * 128 + (w * 4);

  // Load the 8x8 window into registers: 2 aligned float4 per row.
  float win[8][8];
#pragma unroll
  for (int r = 0; r < 8; ++r) {
    float4 a = *reinterpret_cast<const float4*>(src + r * 128);
    float4 b = *reinterpret_cast<const float4*>(src + r * 128 + 4);
    win[r][0] = a.x; win[r][1] = a.y; win[r][2] = a.z; win[r][3] = a.w;
    win[r][4] = b.x; win[r][5] = b.y; win[r][6] = b.z; win[r][7] = b.w;
  }

  float* dst = out + (size_t)t * 64;

#pragma unroll
  for (int oy = 0; oy < 8; ++oy) {
    const int dy = oy - 4;
    float acc[8] = {0.f, 0.f, 0.f, 0.f, 0.f, 0.f, 0.f, 0.f};
#pragma unroll
    for (int i = 0; i < 8; ++i) {
      if (i + dy < 0 || i + dy >= 8) continue;  // compile-time after unroll
#pragma unroll
      for (int ox = 0; ox < 8; ++ox) {
        const int dx = ox - 4;
#pragma unroll
        for (int j = 0; j < 8; ++j) {
          if (j + dx < 0 || j + dx >= 8) continue;  // compile-time
          acc[ox] += win[i][j] * win[i + dy][j + dx];
        }
      }
    }
    float4 s0 = make_float4(acc[0], acc[1], acc[2], acc[3]);
    float4 s1 = make_float4(acc[4], acc[5], acc[6], acc[7]);
    *reinterpret_cast<float4*>(dst + oy * 8)     = s0;
    *reinterpret_cast<float4*>(dst + oy * 8 + 4) = s1;
  }
}

extern "C" void kernel_launch(void* const* d_in, const int* in_sizes, int n_in,
                              void* d_out, int out_size, void* d_ws, size_t ws_size,
                              hipStream_t stream) {
  const float* x = (const float*)d_in[0];
  float* out = (float*)d_out;
  int grid = (NWIN + 255) / 256;
  lacorr2d_kernel<<<grid, 256, 0, stream>>>(x, out);
}